// Round 7
// baseline (418.922 us; speedup 1.0000x reference)
//
#include <hip/hip_runtime.h>
#include <math.h>

// Shapes: B=8, T=16, H=64, W=64, D=256, DK=128, TOP_K=4
// pixels N = B*H*W = 32768 (4096 per batch)
//
// Factorization: out = (sum_t attn_t * hist_t) @ (Wv@Wo)
//                score_t = (q @ (Wq@Wk^T)) . hist_t / sqrt(128)
// hist read exactly once, double-buffered in registers (prefetch distance 2).
// Score path fully fp32 (top-k selection is precision-critical).
//
// R7: the two fp32 GEMM phases are CHUNK-INTERLEAVED into the hist stream
// (qm chunks of 4/8/4 rows just-in-time before their pixels; out chunks of
// 8/6/2 rows as soon as their hbar rows exist). Program order inside each
// wave forces GEMM VALU to overlap the BW-bound stream; chunk sizes >=4 keep
// M1/M2 L2 re-reads under the L2 budget. GEMM A-reads are scalar ds_read_b32
// broadcasts (R5 form; R6's b128 variant regressed).

// ---------------- Kernel P: M1 = Wq@Wk^T, M2 = Wv@Wo (256x256 each) -------
__global__ __launch_bounds__(256) void precompute_weights(
    const float* __restrict__ Wq, const float* __restrict__ Wk,
    const float* __restrict__ Wv, const float* __restrict__ Wo,
    float* __restrict__ M1, float* __restrict__ M2) {
  __shared__ float rowbuf[128];
  int bid = blockIdx.x, tid = threadIdx.x;
  if (bid < 256) {
    if (tid < 128) rowbuf[tid] = Wq[bid * 128 + tid];
    __syncthreads();
    const float4* Wk4 = (const float4*)Wk;
    const float4* rb4 = (const float4*)rowbuf;
    float acc = 0.f;
#pragma unroll 8
    for (int k4 = 0; k4 < 32; ++k4) {
      float4 a = rb4[k4];
      float4 b = Wk4[tid * 32 + k4];
      acc = fmaf(a.x, b.x, acc); acc = fmaf(a.y, b.y, acc);
      acc = fmaf(a.z, b.z, acc); acc = fmaf(a.w, b.w, acc);
    }
    M1[bid * 256 + tid] = acc;
  } else {
    int d = bid - 256;
    if (tid < 128) rowbuf[tid] = Wv[d * 128 + tid];
    __syncthreads();
    float acc = 0.f;
#pragma unroll 8
    for (int k = 0; k < 128; ++k)
      acc = fmaf(rowbuf[k], Wo[k * 256 + tid], acc);
    M2[d * 256 + tid] = acc;
  }
}

// ---------------- Mega-kernel: qm -> attention -> out-projection ----------
// 64 pixels/block, 4 waves, wave w owns rows w*16..w*16+15. NO barriers.
__global__ __launch_bounds__(256, 2) void fused_all(
    const float* __restrict__ query, const float* __restrict__ hist,
    const float* __restrict__ M1, const float* __restrict__ M2,
    float* __restrict__ OUT) {
  __shared__ float As[64][260];  // per-wave 16-row slice: query->qm->hbar
  int tid = threadIdx.x;
  int l = tid & 63;   // lane
  int w = tid >> 6;   // wave
  int pix0 = blockIdx.x * 64;
  int r0 = w * 16;    // this wave's first row

  // hist geometry (float4 units)
  const float4* H4 = (const float4*)hist;
  int b = pix0 >> 12;  // 64-pixel tile never crosses a batch
  int off0 = pix0 & 4095;
  size_t hblk = ((size_t)b * 16 * 4096 + off0) * 64 + l;
  int t_mine = l & 15;
  int gbase = l & 48;  // 16-lane replica group base
  float4* C4 = (float4*)(OUT + (size_t)pix0 * 256);

  // ---- stage own 16 query rows into As ----
  const float4* Qb4 = (const float4*)(query + (size_t)pix0 * 256);
#pragma unroll
  for (int k = 0; k < 16; ++k)
    *(float4*)&As[r0 + k][4 * l] = Qb4[(size_t)(r0 + k) * 64 + l];

  float4 hA[16], hB[16];

#define PREFETCH(HN, PIXROW)                                                \
  {                                                                         \
    size_t nb = hblk + (size_t)(r0 + (PIXROW)) * 64;                        \
    _Pragma("unroll") for (int t = 0; t < 16; ++t)                          \
        (HN)[t] = H4[nb + (size_t)t * 262144];                              \
  }

// NR-row fp32 GEMM chunk vs M1, result -> qm rows (overwrite query in As).
#define CHUNK_QM(RS, NR)                                                    \
  {                                                                         \
    float4 cacc[NR];                                                        \
    _Pragma("unroll") for (int j = 0; j < NR; ++j)                          \
        cacc[j] = make_float4(0.f, 0.f, 0.f, 0.f);                          \
    const float4* B4 = (const float4*)M1;                                   \
    _Pragma("unroll 4") for (int d = 0; d < 256; ++d) {                     \
      float4 bv = B4[d * 64 + l];                                           \
      _Pragma("unroll") for (int j = 0; j < NR; ++j) {                      \
        float a = As[r0 + (RS) + j][d];                                     \
        cacc[j].x = fmaf(a, bv.x, cacc[j].x);                               \
        cacc[j].y = fmaf(a, bv.y, cacc[j].y);                               \
        cacc[j].z = fmaf(a, bv.z, cacc[j].z);                               \
        cacc[j].w = fmaf(a, bv.w, cacc[j].w);                               \
      }                                                                     \
    }                                                                       \
    _Pragma("unroll") for (int j = 0; j < NR; ++j)                          \
        *(float4*)&As[r0 + (RS) + j][4 * l] = cacc[j];                      \
  }

// NR-row fp32 GEMM chunk vs M2, hbar rows (As) -> OUT global.
#define CHUNK_OUT(RS, NR)                                                   \
  {                                                                         \
    float4 cacc[NR];                                                        \
    _Pragma("unroll") for (int j = 0; j < NR; ++j)                          \
        cacc[j] = make_float4(0.f, 0.f, 0.f, 0.f);                          \
    const float4* B4 = (const float4*)M2;                                   \
    _Pragma("unroll 4") for (int d = 0; d < 256; ++d) {                     \
      float4 bv = B4[d * 64 + l];                                           \
      _Pragma("unroll") for (int j = 0; j < NR; ++j) {                      \
        float a = As[r0 + (RS) + j][d];                                     \
        cacc[j].x = fmaf(a, bv.x, cacc[j].x);                               \
        cacc[j].y = fmaf(a, bv.y, cacc[j].y);                               \
        cacc[j].z = fmaf(a, bv.z, cacc[j].z);                               \
        cacc[j].w = fmaf(a, bv.w, cacc[j].w);                               \
      }                                                                     \
    }                                                                       \
    _Pragma("unroll") for (int j = 0; j < NR; ++j)                          \
        C4[(r0 + (RS) + j) * 64 + l] = cacc[j];                             \
  }

// Attention for pixel (r0+IT) using registers HC; hbar -> As row.
#define ATTN_STEP(HC, IT)                                                   \
  {                                                                         \
    int row = r0 + (IT);                                                    \
    float4 q = *(const float4*)&As[row][4 * l];                             \
    float part[16];                                                         \
    _Pragma("unroll") for (int t = 0; t < 16; ++t) {                        \
      float s = HC[t].x * q.x;                                              \
      s = fmaf(HC[t].y, q.y, s);                                            \
      s = fmaf(HC[t].z, q.z, s);                                            \
      s = fmaf(HC[t].w, q.w, s);                                            \
      part[t] = s;                                                          \
    }                                                                       \
    _Pragma("unroll") for (int st = 0; st < 4; ++st) {                      \
      bool hi = (l >> st) & 1;                                              \
      int nt = 8 >> st;                                                     \
      _Pragma("unroll") for (int i = 0; i < nt; ++i) {                      \
        float mine = hi ? part[2 * i + 1] : part[2 * i];                    \
        float oth = hi ? part[2 * i] : part[2 * i + 1];                     \
        part[i] = mine + __shfl_xor(oth, 1 << st);                          \
      }                                                                     \
    }                                                                       \
    float v = part[0];                                                      \
    v += __shfl_xor(v, 16);                                                 \
    v += __shfl_xor(v, 32);                                                 \
    float sc = v * 0.08838834764831845f; /* 1/sqrt(128); t = l&15 */        \
    int rank = 0; /* exact lax.top_k: lowest-index tie-break */             \
    _Pragma("unroll") for (int k = 1; k < 16; ++k) {                        \
      int ot = (t_mine + k) & 15;                                           \
      float o = __shfl(sc, gbase | ot);                                     \
      rank += (o > sc) || (o == sc && ot < t_mine);                         \
    }                                                                       \
    bool chosen = rank < 4;                                                 \
    float earg = sc + (float)(16 - t_mine) * -0.05129329438755058f;         \
    float ex = chosen ? expf(earg) : 0.0f;                                  \
    float Z = ex;                                                           \
    Z += __shfl_xor(Z, 1);                                                  \
    Z += __shfl_xor(Z, 2);                                                  \
    Z += __shfl_xor(Z, 4);                                                  \
    Z += __shfl_xor(Z, 8);                                                  \
    float attn = ex / Z;                                                    \
    float4 hb = make_float4(0.f, 0.f, 0.f, 0.f);                            \
    _Pragma("unroll") for (int t = 0; t < 16; ++t) {                        \
      float a = __shfl(attn, gbase | t); /* uniform in value across wave */ \
      if (a != 0.0f) {                                                      \
        hb.x = fmaf(a, HC[t].x, hb.x);                                      \
        hb.y = fmaf(a, HC[t].y, hb.y);                                      \
        hb.z = fmaf(a, HC[t].z, hb.z);                                      \
        hb.w = fmaf(a, HC[t].w, hb.w);                                      \
      }                                                                     \
    }                                                                       \
    *(float4*)&As[row][4 * l] = hb; /* q already in reg; row wave-owned */  \
  }

  // ---- interleaved schedule: chunks ride under the hist stream ----
  PREFETCH(hA, 0)
  PREFETCH(hB, 1)
  CHUNK_QM(0, 4)                    // rows 0-3 (covered by p0+p1 in flight)
  ATTN_STEP(hA, 0) PREFETCH(hA, 2)
  CHUNK_QM(4, 8)                    // rows 4-11
  ATTN_STEP(hB, 1) PREFETCH(hB, 3)
  CHUNK_QM(12, 4)                   // rows 12-15
  ATTN_STEP(hA, 2) PREFETCH(hA, 4)
  ATTN_STEP(hB, 3) PREFETCH(hB, 5)
  ATTN_STEP(hA, 4) PREFETCH(hA, 6)
  ATTN_STEP(hB, 5) PREFETCH(hB, 7)
  ATTN_STEP(hA, 6) PREFETCH(hA, 8)
  ATTN_STEP(hB, 7) PREFETCH(hB, 9)
  CHUNK_OUT(0, 8)                   // rows 0-7 done -> project & store
  ATTN_STEP(hA, 8) PREFETCH(hA, 10)
  ATTN_STEP(hB, 9) PREFETCH(hB, 11)
  ATTN_STEP(hA, 10) PREFETCH(hA, 12)
  ATTN_STEP(hB, 11) PREFETCH(hB, 13)
  ATTN_STEP(hA, 12) PREFETCH(hA, 14)
  ATTN_STEP(hB, 13) PREFETCH(hB, 15)
  CHUNK_OUT(8, 6)                   // rows 8-13
  ATTN_STEP(hA, 14)
  ATTN_STEP(hB, 15)
  CHUNK_OUT(14, 2)                  // tiny tail
#undef ATTN_STEP
#undef CHUNK_QM
#undef CHUNK_OUT
#undef PREFETCH
}

// --------------------------------------------------------------------------
extern "C" void kernel_launch(void* const* d_in, const int* in_sizes, int n_in,
                              void* d_out, int out_size, void* d_ws,
                              size_t ws_size, hipStream_t stream) {
  const float* query = (const float*)d_in[0];  // [8,64,64,256]
  const float* hist = (const float*)d_in[1];   // [8,16,64,64,256]
  const float* Wq = (const float*)d_in[2];     // [256,128]
  const float* Wk = (const float*)d_in[3];     // [256,128]
  const float* Wv = (const float*)d_in[4];     // [256,128]
  const float* Wo = (const float*)d_in[5];     // [128,256]
  float* out = (float*)d_out;                  // [32768,256]

  float* ws = (float*)d_ws;
  float* M1 = ws;          // 65536 floats
  float* M2 = ws + 65536;  // 65536 floats

  precompute_weights<<<512, 256, 0, stream>>>(Wq, Wk, Wv, Wo, M1, M2);
  fused_all<<<512, 256, 0, stream>>>(query, hist, M1, M2, out);
}

// Round 8
// 294.457 us; speedup vs baseline: 1.4227x; 1.4227x over previous
//
#include <hip/hip_runtime.h>
#include <math.h>

// Shapes: B=8, T=16, H=64, W=64, D=256, DK=128, TOP_K=4
// pixels N = B*H*W = 32768 (4096 per batch)
//
// Factorization: out = (sum_t attn_t * hist_t) @ (Wv@Wo)
//                score_t = (q @ (Wq@Wk^T)) . hist_t / sqrt(128)
// hist read exactly once. Score path fully fp32 (top-k precision-critical).
//
// R8: occupancy doubled vs R5. 32 pixels/block (8 rows/wave) -> As = 33.3KB
// -> 4 blocks/CU; hist pipeline uses lo[8]/hi[8]/nlo[8] tri-buffer (96 VGPR
// vs 128) + __launch_bounds__(256,4) to force VGPR<=128 -> 16 waves/CU.
// Phases stay separate and barrier-free (R7's chunk interleave spilled).

// ---------------- Kernel P: M1 = Wq@Wk^T, M2 = Wv@Wo (256x256 each) -------
__global__ __launch_bounds__(256) void precompute_weights(
    const float* __restrict__ Wq, const float* __restrict__ Wk,
    const float* __restrict__ Wv, const float* __restrict__ Wo,
    float* __restrict__ M1, float* __restrict__ M2) {
  __shared__ float rowbuf[128];
  int bid = blockIdx.x, tid = threadIdx.x;
  if (bid < 256) {
    if (tid < 128) rowbuf[tid] = Wq[bid * 128 + tid];
    __syncthreads();
    const float4* Wk4 = (const float4*)Wk;
    const float4* rb4 = (const float4*)rowbuf;
    float acc = 0.f;
#pragma unroll 8
    for (int k4 = 0; k4 < 32; ++k4) {
      float4 a = rb4[k4];
      float4 b = Wk4[tid * 32 + k4];
      acc = fmaf(a.x, b.x, acc); acc = fmaf(a.y, b.y, acc);
      acc = fmaf(a.z, b.z, acc); acc = fmaf(a.w, b.w, acc);
    }
    M1[bid * 256 + tid] = acc;
  } else {
    int d = bid - 256;
    if (tid < 128) rowbuf[tid] = Wv[d * 128 + tid];
    __syncthreads();
    float acc = 0.f;
#pragma unroll 8
    for (int k = 0; k < 128; ++k)
      acc = fmaf(rowbuf[k], Wo[k * 256 + tid], acc);
    M2[d * 256 + tid] = acc;
  }
}

// ---------------- Mega-kernel: qm -> attention -> out-projection ----------
// 32 pixels/block, 4 waves, wave w owns rows w*8..w*8+7. NO barriers.
__global__ __launch_bounds__(256, 4) void fused_all(
    const float* __restrict__ query, const float* __restrict__ hist,
    const float* __restrict__ M1, const float* __restrict__ M2,
    float* __restrict__ OUT) {
  __shared__ float As[32][260];  // per-wave 8-row slice: query->qm->hbar
  int tid = threadIdx.x;
  int l = tid & 63;   // lane
  int w = tid >> 6;   // wave
  int pix0 = blockIdx.x * 32;
  int r0 = w * 8;     // this wave's first row

  // hist geometry (float4 units)
  const float4* H4 = (const float4*)hist;
  int b = pix0 >> 12;  // 32-pixel tile never crosses a batch (4096%32==0)
  int off0 = pix0 & 4095;
  size_t hblk = ((size_t)b * 16 * 4096 + off0) * 64 + l;
  int t_mine = l & 15;
  int gbase = l & 48;  // 16-lane replica group base

  // ---- prefetch pixel 0's lower half (t=0..7): lands under the qm GEMM
  float4 lo[8], hi[8], nlo[8];
#pragma unroll
  for (int t = 0; t < 8; ++t)
    lo[t] = H4[hblk + (size_t)r0 * 64 + (size_t)t * 262144];

  // ---- phase 0: own 8 rows of qm = query @ M1 (fp32) ----
  {
    const float4* Qb4 = (const float4*)(query + (size_t)pix0 * 256);
#pragma unroll
    for (int k = 0; k < 8; ++k)
      *(float4*)&As[r0 + k][4 * l] = Qb4[(size_t)(r0 + k) * 64 + l];
    float4 cacc[8];
#pragma unroll
    for (int j = 0; j < 8; ++j) cacc[j] = make_float4(0.f, 0.f, 0.f, 0.f);
    const float4* B4 = (const float4*)M1;
#pragma unroll 4
    for (int d = 0; d < 256; ++d) {
      float4 bv = B4[d * 64 + l];
#pragma unroll
      for (int j = 0; j < 8; ++j) {
        float a = As[r0 + j][d];  // uniform -> LDS broadcast
        cacc[j].x = fmaf(a, bv.x, cacc[j].x);
        cacc[j].y = fmaf(a, bv.y, cacc[j].y);
        cacc[j].z = fmaf(a, bv.z, cacc[j].z);
        cacc[j].w = fmaf(a, bv.w, cacc[j].w);
      }
    }
#pragma unroll
    for (int j = 0; j < 8; ++j)
      *(float4*)&As[r0 + j][4 * l] = cacc[j];
  }

  // ---- phase 1: stream hist, score, top-4, softmax, hbar ----
  // Per pixel: issue hi loads (t=8..15) then next pixel's lo loads; compute
  // part[0..7] from resident lo; vmcnt wait pulls in hi (nlo stays in
  // flight); finish, softmax, hbar, store row to As.
#define PIX_STEP(LO, NLO, IT)                                               \
  {                                                                         \
    int row = r0 + (IT);                                                    \
    size_t cb = hblk + (size_t)row * 64;                                    \
    _Pragma("unroll") for (int t = 0; t < 8; ++t)                           \
        hi[t] = H4[cb + (size_t)(t + 8) * 262144];                          \
    if ((IT) < 7) {                                                         \
      _Pragma("unroll") for (int t = 0; t < 8; ++t)                         \
          NLO[t] = H4[cb + 64 + (size_t)t * 262144];                        \
    }                                                                       \
    float4 q = *(const float4*)&As[row][4 * l];                             \
    float part[16];                                                         \
    _Pragma("unroll") for (int t = 0; t < 8; ++t) {                         \
      float s = LO[t].x * q.x;                                              \
      s = fmaf(LO[t].y, q.y, s);                                            \
      s = fmaf(LO[t].z, q.z, s);                                            \
      s = fmaf(LO[t].w, q.w, s);                                            \
      part[t] = s;                                                          \
    }                                                                       \
    _Pragma("unroll") for (int t = 0; t < 8; ++t) {                         \
      float s = hi[t].x * q.x;                                              \
      s = fmaf(hi[t].y, q.y, s);                                            \
      s = fmaf(hi[t].z, q.z, s);                                            \
      s = fmaf(hi[t].w, q.w, s);                                            \
      part[8 + t] = s;                                                      \
    }                                                                       \
    _Pragma("unroll") for (int st = 0; st < 4; ++st) {                      \
      bool hib = (l >> st) & 1;                                             \
      int nt = 8 >> st;                                                     \
      _Pragma("unroll") for (int i = 0; i < nt; ++i) {                      \
        float mine = hib ? part[2 * i + 1] : part[2 * i];                   \
        float oth = hib ? part[2 * i] : part[2 * i + 1];                    \
        part[i] = mine + __shfl_xor(oth, 1 << st);                          \
      }                                                                     \
    }                                                                       \
    float v = part[0];                                                      \
    v += __shfl_xor(v, 16);                                                 \
    v += __shfl_xor(v, 32);                                                 \
    float sc = v * 0.08838834764831845f; /* 1/sqrt(128); t = l&15 */        \
    int rank = 0; /* exact lax.top_k: lowest-index tie-break */             \
    _Pragma("unroll") for (int k = 1; k < 16; ++k) {                        \
      int ot = (t_mine + k) & 15;                                           \
      float o = __shfl(sc, gbase | ot);                                     \
      rank += (o > sc) || (o == sc && ot < t_mine);                         \
    }                                                                       \
    bool chosen = rank < 4;                                                 \
    float earg = sc + (float)(16 - t_mine) * -0.05129329438755058f;         \
    float ex = chosen ? expf(earg) : 0.0f;                                  \
    float Z = ex;                                                           \
    Z += __shfl_xor(Z, 1);                                                  \
    Z += __shfl_xor(Z, 2);                                                  \
    Z += __shfl_xor(Z, 4);                                                  \
    Z += __shfl_xor(Z, 8);                                                  \
    float attn = ex / Z;                                                    \
    float4 hb = make_float4(0.f, 0.f, 0.f, 0.f);                            \
    _Pragma("unroll") for (int t = 0; t < 8; ++t) {                         \
      float a = __shfl(attn, gbase | t);                                    \
      if (a != 0.0f) {                                                      \
        hb.x = fmaf(a, LO[t].x, hb.x);                                      \
        hb.y = fmaf(a, LO[t].y, hb.y);                                      \
        hb.z = fmaf(a, LO[t].z, hb.z);                                      \
        hb.w = fmaf(a, LO[t].w, hb.w);                                      \
      }                                                                     \
    }                                                                       \
    _Pragma("unroll") for (int t = 0; t < 8; ++t) {                         \
      float a = __shfl(attn, gbase | (8 + t));                              \
      if (a != 0.0f) {                                                      \
        hb.x = fmaf(a, hi[t].x, hb.x);                                      \
        hb.y = fmaf(a, hi[t].y, hb.y);                                      \
        hb.z = fmaf(a, hi[t].z, hb.z);                                      \
        hb.w = fmaf(a, hi[t].w, hb.w);                                      \
      }                                                                     \
    }                                                                       \
    *(float4*)&As[row][4 * l] = hb; /* row wave-owned; q already consumed */ \
  }

  for (int it2 = 0; it2 < 4; ++it2) {
    PIX_STEP(lo, nlo, 2 * it2);
    PIX_STEP(nlo, lo, 2 * it2 + 1);
  }
#undef PIX_STEP

  // ---- phase 2: own 8 rows of OUT = As(hbar) @ M2 ----
  {
    float4 cacc[8];
#pragma unroll
    for (int j = 0; j < 8; ++j) cacc[j] = make_float4(0.f, 0.f, 0.f, 0.f);
    const float4* B4 = (const float4*)M2;
#pragma unroll 4
    for (int d = 0; d < 256; ++d) {
      float4 bv = B4[d * 64 + l];
#pragma unroll
      for (int j = 0; j < 8; ++j) {
        float a = As[r0 + j][d];  // uniform -> LDS broadcast
        cacc[j].x = fmaf(a, bv.x, cacc[j].x);
        cacc[j].y = fmaf(a, bv.y, cacc[j].y);
        cacc[j].z = fmaf(a, bv.z, cacc[j].z);
        cacc[j].w = fmaf(a, bv.w, cacc[j].w);
      }
    }
    float4* C4 = (float4*)(OUT + (size_t)pix0 * 256);
#pragma unroll
    for (int j = 0; j < 8; ++j)
      C4[(r0 + j) * 64 + l] = cacc[j];
  }
}

// --------------------------------------------------------------------------
extern "C" void kernel_launch(void* const* d_in, const int* in_sizes, int n_in,
                              void* d_out, int out_size, void* d_ws,
                              size_t ws_size, hipStream_t stream) {
  const float* query = (const float*)d_in[0];  // [8,64,64,256]
  const float* hist = (const float*)d_in[1];   // [8,16,64,64,256]
  const float* Wq = (const float*)d_in[2];     // [256,128]
  const float* Wk = (const float*)d_in[3];     // [256,128]
  const float* Wv = (const float*)d_in[4];     // [256,128]
  const float* Wo = (const float*)d_in[5];     // [128,256]
  float* out = (float*)d_out;                  // [32768,256]

  float* ws = (float*)d_ws;
  float* M1 = ws;          // 65536 floats
  float* M2 = ws + 65536;  // 65536 floats

  precompute_weights<<<512, 256, 0, stream>>>(Wq, Wk, Wv, Wo, M1, M2);
  fused_all<<<1024, 256, 0, stream>>>(query, hist, M1, M2, out);
}

// Round 9
// 234.112 us; speedup vs baseline: 1.7894x; 1.2578x over previous
//
#include <hip/hip_runtime.h>
#include <math.h>

// Shapes: B=8, T=16, H=64, W=64, D=256, DK=128, TOP_K=4
// pixels N = B*H*W = 32768 (4096 per batch)
//
// Factorization: out = (sum_t attn_t * hist_t) @ (Wv@Wo)
//                score_t = (q @ (Wq@Wk^T)) . hist_t / sqrt(128)
// hist read exactly once. Score path fully fp32 (top-k precision-critical).
//
// R9: occupancy-first, spill-free. 32 pixels/block (As = 33.3 KB -> 4
// blocks/CU) + SINGLE-buffer h[16] (64 VGPR h-state, ~105 live total, under
// the 128-reg occupancy cliff) + plain __launch_bounds__(256) (both
// min-waves hints backfired: R8's (256,4) clamped VGPR to 64 -> 213 MB of
// scratch spills). Latency hiding comes from 16 waves/CU TLP, not prefetch.
// All arithmetic bit-identical to R5/R8 (same trees, same order).

// ---------------- Kernel P: M1 = Wq@Wk^T, M2 = Wv@Wo (256x256 each) -------
__global__ __launch_bounds__(256) void precompute_weights(
    const float* __restrict__ Wq, const float* __restrict__ Wk,
    const float* __restrict__ Wv, const float* __restrict__ Wo,
    float* __restrict__ M1, float* __restrict__ M2) {
  __shared__ float rowbuf[128];
  int bid = blockIdx.x, tid = threadIdx.x;
  if (bid < 256) {
    if (tid < 128) rowbuf[tid] = Wq[bid * 128 + tid];
    __syncthreads();
    const float4* Wk4 = (const float4*)Wk;
    const float4* rb4 = (const float4*)rowbuf;
    float acc = 0.f;
#pragma unroll 8
    for (int k4 = 0; k4 < 32; ++k4) {
      float4 a = rb4[k4];
      float4 b = Wk4[tid * 32 + k4];
      acc = fmaf(a.x, b.x, acc); acc = fmaf(a.y, b.y, acc);
      acc = fmaf(a.z, b.z, acc); acc = fmaf(a.w, b.w, acc);
    }
    M1[bid * 256 + tid] = acc;
  } else {
    int d = bid - 256;
    if (tid < 128) rowbuf[tid] = Wv[d * 128 + tid];
    __syncthreads();
    float acc = 0.f;
#pragma unroll 8
    for (int k = 0; k < 128; ++k)
      acc = fmaf(rowbuf[k], Wo[k * 256 + tid], acc);
    M2[d * 256 + tid] = acc;
  }
}

// ---------------- Mega-kernel: qm -> attention -> out-projection ----------
// 32 pixels/block, 4 waves, wave w owns rows w*8..w*8+7. NO barriers.
__global__ __launch_bounds__(256) void fused_all(
    const float* __restrict__ query, const float* __restrict__ hist,
    const float* __restrict__ M1, const float* __restrict__ M2,
    float* __restrict__ OUT) {
  __shared__ float As[32][260];  // per-wave 8-row slice: query->qm->hbar
  int tid = threadIdx.x;
  int l = tid & 63;   // lane
  int w = tid >> 6;   // wave
  int pix0 = blockIdx.x * 32;
  int r0 = w * 8;     // this wave's first row

  // hist geometry (float4 units)
  const float4* H4 = (const float4*)hist;
  int b = pix0 >> 12;  // 32-pixel tile never crosses a batch (4096%32==0)
  int off0 = pix0 & 4095;
  size_t hblk = ((size_t)b * 16 * 4096 + off0) * 64 + l;
  int t_mine = l & 15;
  int gbase = l & 48;  // 16-lane replica group base

  // ---- phase 0: own 8 rows of qm = query @ M1 (fp32) ----
  {
    const float4* Qb4 = (const float4*)(query + (size_t)pix0 * 256);
#pragma unroll
    for (int k = 0; k < 8; ++k)
      *(float4*)&As[r0 + k][4 * l] = Qb4[(size_t)(r0 + k) * 64 + l];
    float4 cacc[8];
#pragma unroll
    for (int j = 0; j < 8; ++j) cacc[j] = make_float4(0.f, 0.f, 0.f, 0.f);
    const float4* B4 = (const float4*)M1;
#pragma unroll 4
    for (int d = 0; d < 256; ++d) {
      float4 bv = B4[d * 64 + l];
#pragma unroll
      for (int j = 0; j < 8; ++j) {
        float a = As[r0 + j][d];  // uniform -> LDS broadcast
        cacc[j].x = fmaf(a, bv.x, cacc[j].x);
        cacc[j].y = fmaf(a, bv.y, cacc[j].y);
        cacc[j].z = fmaf(a, bv.z, cacc[j].z);
        cacc[j].w = fmaf(a, bv.w, cacc[j].w);
      }
    }
#pragma unroll
    for (int j = 0; j < 8; ++j)
      *(float4*)&As[r0 + j][4 * l] = cacc[j];
  }

  // ---- phase 1: stream hist, score, top-4, softmax, hbar ----
  // Single-buffer per pixel: issue 16 loads, compute. Latency covered by
  // 16 waves/CU of TLP (4 blocks/CU), not by per-wave prefetch.
  for (int it = 0; it < 8; ++it) {
    int row = r0 + it;
    size_t cb = hblk + (size_t)row * 64;
    float4 h[16];
#pragma unroll
    for (int t = 0; t < 16; ++t)
      h[t] = H4[cb + (size_t)t * 262144];

    float4 q = *(const float4*)&As[row][4 * l];
    float part[16];
#pragma unroll
    for (int t = 0; t < 16; ++t) {
      float s = h[t].x * q.x;
      s = fmaf(h[t].y, q.y, s);
      s = fmaf(h[t].z, q.z, s);
      s = fmaf(h[t].w, q.w, s);
      part[t] = s;
    }
    // multi-value tree reduce (identical to R5): part[0] -> t=(l&15) group
    // partial; two butterflies finish the 64-lane sum.
#pragma unroll
    for (int st = 0; st < 4; ++st) {
      bool hib = (l >> st) & 1;
      int nt = 8 >> st;
#pragma unroll
      for (int i = 0; i < nt; ++i) {
        float mine = hib ? part[2 * i + 1] : part[2 * i];
        float oth = hib ? part[2 * i] : part[2 * i + 1];
        part[i] = mine + __shfl_xor(oth, 1 << st);
      }
    }
    float v = part[0];
    v += __shfl_xor(v, 16);
    v += __shfl_xor(v, 32);
    float sc = v * 0.08838834764831845f;  // 1/sqrt(128); t = l&15

    // rank-based exact top-4 (lowest-index tie-break == lax.top_k)
    int rank = 0;
#pragma unroll
    for (int k = 1; k < 16; ++k) {
      int ot = (t_mine + k) & 15;
      float o = __shfl(sc, gbase | ot);
      rank += (o > sc) || (o == sc && ot < t_mine);
    }
    bool chosen = rank < 4;

    // decay bias + softmax over the 4 chosen
    float earg = sc + (float)(16 - t_mine) * -0.05129329438755058f;
    float ex = chosen ? expf(earg) : 0.0f;
    float Z = ex;
    Z += __shfl_xor(Z, 1);
    Z += __shfl_xor(Z, 2);
    Z += __shfl_xor(Z, 4);
    Z += __shfl_xor(Z, 8);
    float attn = ex / Z;  // weight for t=l&15, replicated per group

    // hbar = sum_t attn[t] * h[t]
    float4 hb = make_float4(0.f, 0.f, 0.f, 0.f);
#pragma unroll
    for (int t = 0; t < 16; ++t) {
      float a = __shfl(attn, gbase | t);  // wave-uniform value
      if (a != 0.0f) {
        hb.x = fmaf(a, h[t].x, hb.x);
        hb.y = fmaf(a, h[t].y, hb.y);
        hb.z = fmaf(a, h[t].z, hb.z);
        hb.w = fmaf(a, h[t].w, hb.w);
      }
    }
    *(float4*)&As[row][4 * l] = hb;  // row wave-owned; q already consumed
  }

  // ---- phase 2: own 8 rows of OUT = As(hbar) @ M2 ----
  {
    float4 cacc[8];
#pragma unroll
    for (int j = 0; j < 8; ++j) cacc[j] = make_float4(0.f, 0.f, 0.f, 0.f);
    const float4* B4 = (const float4*)M2;
#pragma unroll 4
    for (int d = 0; d < 256; ++d) {
      float4 bv = B4[d * 64 + l];
#pragma unroll
      for (int j = 0; j < 8; ++j) {
        float a = As[r0 + j][d];  // uniform -> LDS broadcast
        cacc[j].x = fmaf(a, bv.x, cacc[j].x);
        cacc[j].y = fmaf(a, bv.y, cacc[j].y);
        cacc[j].z = fmaf(a, bv.z, cacc[j].z);
        cacc[j].w = fmaf(a, bv.w, cacc[j].w);
      }
    }
    float4* C4 = (float4*)(OUT + (size_t)pix0 * 256);
#pragma unroll
    for (int j = 0; j < 8; ++j)
      C4[(r0 + j) * 64 + l] = cacc[j];
  }
}

// --------------------------------------------------------------------------
extern "C" void kernel_launch(void* const* d_in, const int* in_sizes, int n_in,
                              void* d_out, int out_size, void* d_ws,
                              size_t ws_size, hipStream_t stream) {
  const float* query = (const float*)d_in[0];  // [8,64,64,256]
  const float* hist = (const float*)d_in[1];   // [8,16,64,64,256]
  const float* Wq = (const float*)d_in[2];     // [256,128]
  const float* Wk = (const float*)d_in[3];     // [256,128]
  const float* Wv = (const float*)d_in[4];     // [256,128]
  const float* Wo = (const float*)d_in[5];     // [128,256]
  float* out = (float*)d_out;                  // [32768,256]

  float* ws = (float*)d_ws;
  float* M1 = ws;          // 65536 floats
  float* M2 = ws + 65536;  // 65536 floats

  precompute_weights<<<512, 256, 0, stream>>>(Wq, Wk, Wv, Wo, M1, M2);
  fused_all<<<1024, 256, 0, stream>>>(query, hist, M1, M2, out);
}

// Round 10
// 199.225 us; speedup vs baseline: 2.1028x; 1.1751x over previous
//
#include <hip/hip_runtime.h>
#include <math.h>

// Shapes: B=8, T=16, H=64, W=64, D=256, DK=128, TOP_K=4
// pixels N = B*H*W = 32768 (4096 per batch)
//
// Factorization: out = (sum_t attn_t * hist_t) @ (Wv@Wo)
//                score_t = (q @ (Wq@Wk^T)) . hist_t / sqrt(128)
// hist read exactly once, double-buffered in registers.
// Score path fully fp32 (top-k selection is precision-critical).
//
// R10 = R5 champion base (64px/block, 2 blocks/CU, barrier-free, reg
// double-buffer) + PIXEL-INTERLEAVED wave mapping: wave w owns pixels
// pix0 + w + 4*i (not a contiguous 16-px slab). The block's 4 waves then
// read consecutive 1KB chunks of each hist t-stream simultaneously ->
// 4KB effective DRAM bursts, 4x fewer concurrent streams. All per-pixel
// arithmetic bit-identical to R5.

// ---------------- Kernel P: M1 = Wq@Wk^T, M2 = Wv@Wo (256x256 each) -------
__global__ __launch_bounds__(256) void precompute_weights(
    const float* __restrict__ Wq, const float* __restrict__ Wk,
    const float* __restrict__ Wv, const float* __restrict__ Wo,
    float* __restrict__ M1, float* __restrict__ M2) {
  __shared__ float rowbuf[128];
  int bid = blockIdx.x, tid = threadIdx.x;
  if (bid < 256) {
    if (tid < 128) rowbuf[tid] = Wq[bid * 128 + tid];
    __syncthreads();
    const float4* Wk4 = (const float4*)Wk;
    const float4* rb4 = (const float4*)rowbuf;
    float acc = 0.f;
#pragma unroll 8
    for (int k4 = 0; k4 < 32; ++k4) {
      float4 a = rb4[k4];
      float4 b = Wk4[tid * 32 + k4];
      acc = fmaf(a.x, b.x, acc); acc = fmaf(a.y, b.y, acc);
      acc = fmaf(a.z, b.z, acc); acc = fmaf(a.w, b.w, acc);
    }
    M1[bid * 256 + tid] = acc;
  } else {
    int d = bid - 256;
    if (tid < 128) rowbuf[tid] = Wv[d * 128 + tid];
    __syncthreads();
    float acc = 0.f;
#pragma unroll 8
    for (int k = 0; k < 128; ++k)
      acc = fmaf(rowbuf[k], Wo[k * 256 + tid], acc);
    M2[d * 256 + tid] = acc;
  }
}

// ---------------- Mega-kernel: qm -> attention -> out-projection ----------
// 64 pixels/block, 4 waves, wave w owns rows {w + 4*i}. NO barriers.
__global__ __launch_bounds__(256, 2) void fused_all(
    const float* __restrict__ query, const float* __restrict__ hist,
    const float* __restrict__ M1, const float* __restrict__ M2,
    float* __restrict__ OUT) {
  __shared__ float As[64][260];  // per-wave 16-row slice: query->qm->hbar
  int tid = threadIdx.x;
  int l = tid & 63;   // lane
  int w = tid >> 6;   // wave
  int pix0 = blockIdx.x * 64;

  // hist geometry (float4 units)
  const float4* H4 = (const float4*)hist;
  int b = pix0 >> 12;  // 64-pixel tile never crosses a batch
  int off0 = pix0 & 4095;
  size_t hblk = ((size_t)b * 16 * 4096 + off0) * 64 + l;
  int t_mine = l & 15;
  int gbase = l & 48;  // 16-lane replica group base

  // ---------- phase 0: own 16 rows {w+4j} of qm = query @ M1 ----------
  {
    const float4* Qb4 = (const float4*)(query + (size_t)pix0 * 256);
#pragma unroll
    for (int k = 0; k < 16; ++k)
      *(float4*)&As[w + 4 * k][4 * l] = Qb4[(size_t)(w + 4 * k) * 64 + l];
    float4 acc[16];
#pragma unroll
    for (int j = 0; j < 16; ++j) acc[j] = make_float4(0.f, 0.f, 0.f, 0.f);
    const float4* B4 = (const float4*)M1;
#pragma unroll 4
    for (int d = 0; d < 256; ++d) {
      float4 bv = B4[d * 64 + l];
#pragma unroll
      for (int j = 0; j < 16; ++j) {
        float a = As[w + 4 * j][d];  // uniform -> LDS broadcast
        acc[j].x = fmaf(a, bv.x, acc[j].x);
        acc[j].y = fmaf(a, bv.y, acc[j].y);
        acc[j].z = fmaf(a, bv.z, acc[j].z);
        acc[j].w = fmaf(a, bv.w, acc[j].w);
      }
    }
    // all reads of own query rows done (program order) -> overwrite with qm
#pragma unroll
    for (int j = 0; j < 16; ++j)
      *(float4*)&As[w + 4 * j][4 * l] = acc[j];
  }

  // ---------- phase 1: stream hist, score, top-4, softmax, hbar ----------
  float4 hA[16], hB[16];
#pragma unroll
  for (int t = 0; t < 16; ++t)  // pixel row = w
    hA[t] = H4[hblk + (size_t)w * 64 + (size_t)t * 262144];

#define ATTN_STEP(HC, HN, IT, DOPRE)                                        \
  {                                                                         \
    int row = w + 4 * (IT);                                                 \
    if (DOPRE) { /* prefetch next pixel (row+4) into HN */                  \
      size_t nb = hblk + (size_t)(row + 4) * 64;                            \
      _Pragma("unroll") for (int t = 0; t < 16; ++t)                        \
          HN[t] = H4[nb + (size_t)t * 262144];                              \
    }                                                                       \
    float4 q = *(const float4*)&As[row][4 * l];                             \
    float part[16];                                                         \
    _Pragma("unroll") for (int t = 0; t < 16; ++t) {                        \
      float s = HC[t].x * q.x;                                              \
      s = fmaf(HC[t].y, q.y, s);                                            \
      s = fmaf(HC[t].z, q.z, s);                                            \
      s = fmaf(HC[t].w, q.w, s);                                            \
      part[t] = s;                                                          \
    }                                                                       \
    _Pragma("unroll") for (int st = 0; st < 4; ++st) {                      \
      bool hi = (l >> st) & 1;                                              \
      int nt = 8 >> st;                                                     \
      _Pragma("unroll") for (int i = 0; i < nt; ++i) {                      \
        float mine = hi ? part[2 * i + 1] : part[2 * i];                    \
        float oth = hi ? part[2 * i] : part[2 * i + 1];                     \
        part[i] = mine + __shfl_xor(oth, 1 << st);                          \
      }                                                                     \
    }                                                                       \
    float v = part[0];                                                      \
    v += __shfl_xor(v, 16);                                                 \
    v += __shfl_xor(v, 32);                                                 \
    float sc = v * 0.08838834764831845f; /* 1/sqrt(128); t = l&15 */        \
    int rank = 0; /* exact lax.top_k: lowest-index tie-break */             \
    _Pragma("unroll") for (int k = 1; k < 16; ++k) {                        \
      int ot = (t_mine + k) & 15;                                           \
      float o = __shfl(sc, gbase | ot);                                     \
      rank += (o > sc) || (o == sc && ot < t_mine);                         \
    }                                                                       \
    bool chosen = rank < 4;                                                 \
    float earg = sc + (float)(16 - t_mine) * -0.05129329438755058f;         \
    float ex = chosen ? expf(earg) : 0.0f;                                  \
    float Z = ex;                                                           \
    Z += __shfl_xor(Z, 1);                                                  \
    Z += __shfl_xor(Z, 2);                                                  \
    Z += __shfl_xor(Z, 4);                                                  \
    Z += __shfl_xor(Z, 8);                                                  \
    float attn = ex / Z;                                                    \
    float4 hb = make_float4(0.f, 0.f, 0.f, 0.f);                            \
    _Pragma("unroll") for (int t = 0; t < 16; ++t) {                        \
      float a = __shfl(attn, gbase | t); /* uniform in value across wave */ \
      if (a != 0.0f) {                                                      \
        hb.x = fmaf(a, HC[t].x, hb.x);                                      \
        hb.y = fmaf(a, HC[t].y, hb.y);                                      \
        hb.z = fmaf(a, HC[t].z, hb.z);                                      \
        hb.w = fmaf(a, HC[t].w, hb.w);                                      \
      }                                                                     \
    }                                                                       \
    *(float4*)&As[row][4 * l] = hb; /* q already in reg; row wave-owned */  \
  }

  for (int it2 = 0; it2 < 8; ++it2) {
    ATTN_STEP(hA, hB, 2 * it2, true);
    ATTN_STEP(hB, hA, 2 * it2 + 1, it2 < 7);
  }
#undef ATTN_STEP

  // ---------- phase 2: own 16 rows {w+4j} of OUT = As(hbar) @ M2 ----------
  {
    float4 acc[16];
#pragma unroll
    for (int j = 0; j < 16; ++j) acc[j] = make_float4(0.f, 0.f, 0.f, 0.f);
    const float4* B4 = (const float4*)M2;
#pragma unroll 4
    for (int d = 0; d < 256; ++d) {
      float4 bv = B4[d * 64 + l];
#pragma unroll
      for (int j = 0; j < 16; ++j) {
        float a = As[w + 4 * j][d];  // uniform -> LDS broadcast
        acc[j].x = fmaf(a, bv.x, acc[j].x);
        acc[j].y = fmaf(a, bv.y, acc[j].y);
        acc[j].z = fmaf(a, bv.z, acc[j].z);
        acc[j].w = fmaf(a, bv.w, acc[j].w);
      }
    }
    float4* C4 = (float4*)(OUT + (size_t)pix0 * 256);
#pragma unroll
    for (int j = 0; j < 16; ++j)
      C4[(w + 4 * j) * 64 + l] = acc[j];
  }
}

// --------------------------------------------------------------------------
extern "C" void kernel_launch(void* const* d_in, const int* in_sizes, int n_in,
                              void* d_out, int out_size, void* d_ws,
                              size_t ws_size, hipStream_t stream) {
  const float* query = (const float*)d_in[0];  // [8,64,64,256]
  const float* hist = (const float*)d_in[1];   // [8,16,64,64,256]
  const float* Wq = (const float*)d_in[2];     // [256,128]
  const float* Wk = (const float*)d_in[3];     // [256,128]
  const float* Wv = (const float*)d_in[4];     // [256,128]
  const float* Wo = (const float*)d_in[5];     // [128,256]
  float* out = (float*)d_out;                  // [32768,256]

  float* ws = (float*)d_ws;
  float* M1 = ws;          // 65536 floats
  float* M2 = ws + 65536;  // 65536 floats

  precompute_weights<<<512, 256, 0, stream>>>(Wq, Wk, Wv, Wo, M1, M2);
  fused_all<<<512, 256, 0, stream>>>(query, hist, M1, M2, out);
}